// Round 1
// baseline (386.546 us; speedup 1.0000x reference)
//
#include <hip/hip_runtime.h>
#include <math.h>

// Problem constants (fixed by setup_inputs): x is (8,1024,1024,2) fp32, k=61
#define NB 8
#define HH 1024
#define WW 1024
#define CC 2
#define RAD 30
#define KS 61
#define ROWSZ (WW * CC)        /* 2048 floats per row */
#define IMGSZ (HH * ROWSZ)     /* 2097152 floats per image */
#define NCOL (NB * ROWSZ)      /* 16384 independent columns */
#define SEGH 128
#define NSEG (HH / SEGH)       /* 8 */
#define EPSV 1e-7f
#define SCALEV (1.0f / (float)(KS * KS * CC))  /* 1/7442, keras divides by k*k*C */

// ---------------------------------------------------------------------------
// K1: vertical box-sum (61-tap, zero-padded) of x. Sliding running sum per
// column; 8 h-segments per column for parallelism. Coalesced: consecutive
// lanes = consecutive (w,c).
__global__ __launch_bounds__(256) void vbox_kernel(const float* __restrict__ in,
                                                   float* __restrict__ out) {
    int tid = blockIdx.x * 256 + threadIdx.x;
    int col = tid & (NCOL - 1);
    int seg = tid / NCOL;
    int n = col / ROWSZ;
    int wc = col & (ROWSZ - 1);
    const float* ip = in + (size_t)n * IMGSZ + wc;
    float* op = out + (size_t)n * IMGSZ + wc;
    int h0 = seg * SEGH;
    float S = 0.f;
    int lo = h0 - RAD; if (lo < 0) lo = 0;
    for (int h = lo; h < h0 + RAD; ++h) S += ip[h * ROWSZ];
    for (int ho = h0; ho < h0 + SEGH; ++ho) {
        int ha = ho + RAD;
        if (ha < HH) S += ip[ha * ROWSZ];
        op[ho * ROWSZ] = S;
        int hb = ho - RAD;
        if (hb >= 0) S -= ip[hb * ROWSZ];
    }
}

// K3: vertical dual box-sum of out and out*out (read 'out' once).
__global__ __launch_bounds__(256) void vbox2_kernel(const float* __restrict__ in,
                                                    float* __restrict__ o1,
                                                    float* __restrict__ o2) {
    int tid = blockIdx.x * 256 + threadIdx.x;
    int col = tid & (NCOL - 1);
    int seg = tid / NCOL;
    int n = col / ROWSZ;
    int wc = col & (ROWSZ - 1);
    const float* ip = in + (size_t)n * IMGSZ + wc;
    float* p1 = o1 + (size_t)n * IMGSZ + wc;
    float* p2 = o2 + (size_t)n * IMGSZ + wc;
    int h0 = seg * SEGH;
    float S = 0.f, S2 = 0.f;
    int lo = h0 - RAD; if (lo < 0) lo = 0;
    for (int h = lo; h < h0 + RAD; ++h) {
        float v = ip[h * ROWSZ];
        S += v; S2 += v * v;
    }
    for (int ho = h0; ho < h0 + SEGH; ++ho) {
        int ha = ho + RAD;
        if (ha < HH) { float v = ip[ha * ROWSZ]; S += v; S2 += v * v; }
        p1[ho * ROWSZ] = S;
        p2[ho * ROWSZ] = S2;
        int hb = ho - RAD;
        if (hb >= 0) { float v = ip[hb * ROWSZ]; S -= v; S2 -= v * v; }
    }
}

__device__ inline float wave_incl_scan(float v) {
    int lane = threadIdx.x & 63;
    #pragma unroll
    for (int d = 1; d < 64; d <<= 1) {
        float o = __shfl_up(v, d, 64);
        if (lane >= d) v += o;
    }
    return v;
}

// K2: horizontal box of vertical sums (prefix-sum per row) + out = x - s*box.
// One block per (n,h) row.
__global__ __launch_bounds__(256) void hbox_sub_kernel(const float* __restrict__ vsum,
                                                       const float* __restrict__ x,
                                                       float* __restrict__ out) {
    __shared__ float ch[2][WW];   // deinterleaved channels
    __shared__ float wtot[4];
    int t = threadIdx.x;
    size_t g = (size_t)blockIdx.x * ROWSZ;
    const float2* vrow = (const float2*)(vsum + g);
    #pragma unroll
    for (int i = 0; i < 4; ++i) {
        int w = t + 256 * i;
        float2 v = vrow[w];
        ch[0][w] = v.x; ch[1][w] = v.y;
    }
    __syncthreads();
    // per-thread serial chunk of 8 + wave scan of partials (2 waves/channel)
    int c = t >> 7, j = t & 127, base = j * 8;
    float v[8]; float run = 0.f;
    #pragma unroll
    for (int i = 0; i < 8; ++i) { run += ch[c][base + i]; v[i] = run; }
    float incl = wave_incl_scan(run);
    int wid = t >> 6;
    if ((t & 63) == 63) wtot[wid] = incl;
    __syncthreads();
    float off = incl - run;
    if (wid & 1) off += wtot[wid - 1];
    #pragma unroll
    for (int i = 0; i < 8; ++i) ch[c][base + i] = off + v[i];
    __syncthreads();
    // outputs: box(w) = P[min(w+30,1023)] - (w>=31 ? P[w-31] : 0)
    #pragma unroll
    for (int i = 0; i < 8; ++i) {
        int e = t + 256 * i;
        int w = e >> 1, cc2 = e & 1;
        int hi = w + RAD; if (hi > WW - 1) hi = WW - 1;
        float s = ch[cc2][hi];
        int lo2 = w - RAD - 1;
        if (lo2 >= 0) s -= ch[cc2][lo2];
        out[g + e] = x[g + e] - SCALEV * s;
    }
}

// K4: horizontal box of both vertical sums + finalize y = out / (sqrt(c2-c1^2)+eps).
// Reads/overwrites 'out' (d_out) in place.
__global__ __launch_bounds__(256) void hbox_final_kernel(const float* __restrict__ s1v,
                                                         const float* __restrict__ s2v,
                                                         float* __restrict__ out) {
    __shared__ float ch[4][WW];   // [0..1]=sum channels, [2..3]=sumsq channels
    int t = threadIdx.x;
    size_t g = (size_t)blockIdx.x * ROWSZ;
    const float2* arow = (const float2*)(s1v + g);
    const float2* brow = (const float2*)(s2v + g);
    #pragma unroll
    for (int i = 0; i < 4; ++i) {
        int w = t + 256 * i;
        float2 a = arow[w]; ch[0][w] = a.x; ch[1][w] = a.y;
        float2 b = brow[w]; ch[2][w] = b.x; ch[3][w] = b.y;
    }
    __syncthreads();
    // 4 arrays x 64 chunks of 16; one wave per array -> wave scan only
    int a = t >> 6, j = t & 63, base = j * 16;
    float v[16]; float run = 0.f;
    #pragma unroll
    for (int i = 0; i < 16; ++i) { run += ch[a][base + i]; v[i] = run; }
    float incl = wave_incl_scan(run);
    float off = incl - run;
    #pragma unroll
    for (int i = 0; i < 16; ++i) ch[a][base + i] = off + v[i];
    __syncthreads();
    #pragma unroll
    for (int i = 0; i < 8; ++i) {
        int e = t + 256 * i;
        int w = e >> 1, cc2 = e & 1;
        int hi = w + RAD; if (hi > WW - 1) hi = WW - 1;
        int lo2 = w - RAD - 1;
        float s1 = ch[cc2][hi];
        float s2 = ch[2 + cc2][hi];
        if (lo2 >= 0) { s1 -= ch[cc2][lo2]; s2 -= ch[2 + cc2][lo2]; }
        float c1 = SCALEV * s1;
        float c2 = SCALEV * s2;
        float var = c2 - c1 * c1;
        float stdv = sqrtf(fmaxf(var, 0.f)) + EPSV;
        out[g + e] = out[g + e] / stdv;
    }
}

extern "C" void kernel_launch(void* const* d_in, const int* in_sizes, int n_in,
                              void* d_out, int out_size, void* d_ws, size_t ws_size,
                              hipStream_t stream) {
    const float* x = (const float*)d_in[0];
    float* out = (float*)d_out;
    float* wsf = (float*)d_ws;
    float* V1 = wsf;                              // 64 MB: vert box sums (reused)
    float* V3 = wsf + (size_t)NB * IMGSZ;         // 64 MB: vert box of out^2

    // out = x - s * Box(x)
    vbox_kernel<<<NCOL * NSEG / 256, 256, 0, stream>>>(x, V1);
    hbox_sub_kernel<<<NB * HH, 256, 0, stream>>>(V1, x, out);
    // c1 = s*Box(out), c2 = s*Box(out^2); y = out / (sqrt(c2-c1^2)+eps)
    vbox2_kernel<<<NCOL * NSEG / 256, 256, 0, stream>>>(out, V1, V3);
    hbox_final_kernel<<<NB * HH, 256, 0, stream>>>(V1, V3, out);
}

// Round 2
// 239.863 us; speedup vs baseline: 1.6115x; 1.6115x over previous
//
#include <hip/hip_runtime.h>
#include <math.h>

// Problem constants (fixed by setup_inputs): x is (8,1024,1024,2) fp32, k=61
#define NB 8
#define HH 1024
#define WW 1024
#define CC 2
#define RAD 30
#define KS 61
#define ROWSZ (WW * CC)        /* 2048 floats per row */
#define IMGSZ (HH * ROWSZ)     /* 2097152 floats per image */
#define STR (ROWSZ / 2)        /* 1024 float2 per row */
#define NCOL2 (NB * STR)       /* 8192 independent float2 columns */
#define VSEGH 64
#define VNSEG (HH / VSEGH)     /* 16 */
#define EPSV 1e-7f
#define SCALEV (1.0f / (float)(KS * KS * CC))  /* 1/7442, keras divides by k*k*C */

// ---------------------------------------------------------------------------
// K1: vertical box-sum (61-tap, zero-padded) of x. Sliding running sum per
// float2 column; 16 h-segments. Unroll-4 with batched leading+trailing loads
// for MLP (8 loads in flight per wave -> ~4KB, hides HBM latency at 2 w/SIMD).
__global__ __launch_bounds__(256) void vbox_kernel(const float* __restrict__ in,
                                                   float* __restrict__ out) {
    int tid = blockIdx.x * 256 + threadIdx.x;
    int col = tid & (NCOL2 - 1);
    int seg = tid >> 13;               // tid / NCOL2; block-uniform
    int n = col / STR;
    int wc = col & (STR - 1);
    const float2* ip = (const float2*)(in + (size_t)n * IMGSZ) + wc;
    float2* op = (float2*)(out + (size_t)n * IMGSZ) + wc;
    int h0 = seg * VSEGH;
    float Sx = 0.f, Sy = 0.f;
    int lo = h0 - RAD; if (lo < 0) lo = 0;
    int hiex = h0 + RAD;
    int h = lo;
    for (; h + 4 <= hiex; h += 4) {
        float2 v0 = ip[(h + 0) * STR];
        float2 v1 = ip[(h + 1) * STR];
        float2 v2 = ip[(h + 2) * STR];
        float2 v3 = ip[(h + 3) * STR];
        Sx += v0.x + v1.x + v2.x + v3.x;
        Sy += v0.y + v1.y + v2.y + v3.y;
    }
    for (; h < hiex; ++h) { float2 v = ip[h * STR]; Sx += v.x; Sy += v.y; }
    for (int ho = h0; ho < h0 + VSEGH; ho += 4) {
        float2 a[4], b[4];
        #pragma unroll
        for (int i = 0; i < 4; ++i) {
            int ha = ho + i + RAD;
            a[i] = (ha < HH) ? ip[ha * STR] : make_float2(0.f, 0.f);
        }
        #pragma unroll
        for (int i = 0; i < 4; ++i) {
            int hb = ho + i - RAD;
            b[i] = (hb >= 0) ? ip[hb * STR] : make_float2(0.f, 0.f);
        }
        #pragma unroll
        for (int i = 0; i < 4; ++i) {
            Sx += a[i].x; Sy += a[i].y;
            op[(ho + i) * STR] = make_float2(Sx, Sy);
            Sx -= b[i].x; Sy -= b[i].y;
        }
    }
}

// K3: vertical dual box-sum of out and out*out (read 'out' once per tap).
__global__ __launch_bounds__(256) void vbox2_kernel(const float* __restrict__ in,
                                                    float* __restrict__ o1,
                                                    float* __restrict__ o2) {
    int tid = blockIdx.x * 256 + threadIdx.x;
    int col = tid & (NCOL2 - 1);
    int seg = tid >> 13;
    int n = col / STR;
    int wc = col & (STR - 1);
    const float2* ip = (const float2*)(in + (size_t)n * IMGSZ) + wc;
    float2* p1 = (float2*)(o1 + (size_t)n * IMGSZ) + wc;
    float2* p2 = (float2*)(o2 + (size_t)n * IMGSZ) + wc;
    int h0 = seg * VSEGH;
    float Sx = 0.f, Sy = 0.f, Qx = 0.f, Qy = 0.f;
    int lo = h0 - RAD; if (lo < 0) lo = 0;
    int hiex = h0 + RAD;
    int h = lo;
    for (; h + 4 <= hiex; h += 4) {
        float2 v0 = ip[(h + 0) * STR];
        float2 v1 = ip[(h + 1) * STR];
        float2 v2 = ip[(h + 2) * STR];
        float2 v3 = ip[(h + 3) * STR];
        Sx += v0.x + v1.x + v2.x + v3.x;
        Sy += v0.y + v1.y + v2.y + v3.y;
        Qx += v0.x * v0.x + v1.x * v1.x + v2.x * v2.x + v3.x * v3.x;
        Qy += v0.y * v0.y + v1.y * v1.y + v2.y * v2.y + v3.y * v3.y;
    }
    for (; h < hiex; ++h) {
        float2 v = ip[h * STR];
        Sx += v.x; Sy += v.y; Qx += v.x * v.x; Qy += v.y * v.y;
    }
    for (int ho = h0; ho < h0 + VSEGH; ho += 4) {
        float2 a[4], b[4];
        #pragma unroll
        for (int i = 0; i < 4; ++i) {
            int ha = ho + i + RAD;
            a[i] = (ha < HH) ? ip[ha * STR] : make_float2(0.f, 0.f);
        }
        #pragma unroll
        for (int i = 0; i < 4; ++i) {
            int hb = ho + i - RAD;
            b[i] = (hb >= 0) ? ip[hb * STR] : make_float2(0.f, 0.f);
        }
        #pragma unroll
        for (int i = 0; i < 4; ++i) {
            Sx += a[i].x; Sy += a[i].y;
            Qx += a[i].x * a[i].x; Qy += a[i].y * a[i].y;
            p1[(ho + i) * STR] = make_float2(Sx, Sy);
            p2[(ho + i) * STR] = make_float2(Qx, Qy);
            Sx -= b[i].x; Sy -= b[i].y;
            Qx -= b[i].x * b[i].x; Qy -= b[i].y * b[i].y;
        }
    }
}

__device__ inline float wave_incl_scan(float v) {
    int lane = threadIdx.x & 63;
    #pragma unroll
    for (int d = 1; d < 64; d <<= 1) {
        float o = __shfl_up(v, d, 64);
        if (lane >= d) v += o;
    }
    return v;
}

// K2: horizontal box of vertical sums (prefix-sum per row) + out = x - s*box.
// One block per (n,h) row.
__global__ __launch_bounds__(256) void hbox_sub_kernel(const float* __restrict__ vsum,
                                                       const float* __restrict__ x,
                                                       float* __restrict__ out) {
    __shared__ float ch[2][WW];   // deinterleaved channels
    __shared__ float wtot[4];
    int t = threadIdx.x;
    size_t g = (size_t)blockIdx.x * ROWSZ;
    const float2* vrow = (const float2*)(vsum + g);
    #pragma unroll
    for (int i = 0; i < 4; ++i) {
        int w = t + 256 * i;
        float2 v = vrow[w];
        ch[0][w] = v.x; ch[1][w] = v.y;
    }
    __syncthreads();
    // per-thread serial chunk of 8 + wave scan of partials (2 waves/channel)
    int c = t >> 7, j = t & 127, base = j * 8;
    float v[8]; float run = 0.f;
    #pragma unroll
    for (int i = 0; i < 8; ++i) { run += ch[c][base + i]; v[i] = run; }
    float incl = wave_incl_scan(run);
    int wid = t >> 6;
    if ((t & 63) == 63) wtot[wid] = incl;
    __syncthreads();
    float off = incl - run;
    if (wid & 1) off += wtot[wid - 1];
    #pragma unroll
    for (int i = 0; i < 8; ++i) ch[c][base + i] = off + v[i];
    __syncthreads();
    // outputs: box(w) = P[min(w+30,1023)] - (w>=31 ? P[w-31] : 0)
    #pragma unroll
    for (int i = 0; i < 8; ++i) {
        int e = t + 256 * i;
        int w = e >> 1, cc2 = e & 1;
        int hi = w + RAD; if (hi > WW - 1) hi = WW - 1;
        float s = ch[cc2][hi];
        int lo2 = w - RAD - 1;
        if (lo2 >= 0) s -= ch[cc2][lo2];
        out[g + e] = x[g + e] - SCALEV * s;
    }
}

// K4: horizontal box of both vertical sums + finalize y = out / (sqrt(c2-c1^2)+eps).
// Reads/overwrites 'out' (d_out) in place.
__global__ __launch_bounds__(256) void hbox_final_kernel(const float* __restrict__ s1v,
                                                         const float* __restrict__ s2v,
                                                         float* __restrict__ out) {
    __shared__ float ch[4][WW];   // [0..1]=sum channels, [2..3]=sumsq channels
    int t = threadIdx.x;
    size_t g = (size_t)blockIdx.x * ROWSZ;
    const float2* arow = (const float2*)(s1v + g);
    const float2* brow = (const float2*)(s2v + g);
    #pragma unroll
    for (int i = 0; i < 4; ++i) {
        int w = t + 256 * i;
        float2 a = arow[w]; ch[0][w] = a.x; ch[1][w] = a.y;
        float2 b = brow[w]; ch[2][w] = b.x; ch[3][w] = b.y;
    }
    __syncthreads();
    // 4 arrays x 64 chunks of 16; one wave per array -> wave scan only
    int a = t >> 6, j = t & 63, base = j * 16;
    float v[16]; float run = 0.f;
    #pragma unroll
    for (int i = 0; i < 16; ++i) { run += ch[a][base + i]; v[i] = run; }
    float incl = wave_incl_scan(run);
    float off = incl - run;
    #pragma unroll
    for (int i = 0; i < 16; ++i) ch[a][base + i] = off + v[i];
    __syncthreads();
    #pragma unroll
    for (int i = 0; i < 8; ++i) {
        int e = t + 256 * i;
        int w = e >> 1, cc2 = e & 1;
        int hi = w + RAD; if (hi > WW - 1) hi = WW - 1;
        int lo2 = w - RAD - 1;
        float s1 = ch[cc2][hi];
        float s2 = ch[2 + cc2][hi];
        if (lo2 >= 0) { s1 -= ch[cc2][lo2]; s2 -= ch[2 + cc2][lo2]; }
        float c1 = SCALEV * s1;
        float c2 = SCALEV * s2;
        float var = c2 - c1 * c1;
        float stdv = sqrtf(fmaxf(var, 0.f)) + EPSV;
        out[g + e] = out[g + e] / stdv;
    }
}

extern "C" void kernel_launch(void* const* d_in, const int* in_sizes, int n_in,
                              void* d_out, int out_size, void* d_ws, size_t ws_size,
                              hipStream_t stream) {
    const float* x = (const float*)d_in[0];
    float* out = (float*)d_out;
    float* wsf = (float*)d_ws;
    float* V1 = wsf;                              // 64 MB: vert box sums (reused)
    float* V3 = wsf + (size_t)NB * IMGSZ;         // 64 MB: vert box of out^2

    // out = x - s * Box(x)
    vbox_kernel<<<(NCOL2 * VNSEG) / 256, 256, 0, stream>>>(x, V1);
    hbox_sub_kernel<<<NB * HH, 256, 0, stream>>>(V1, x, out);
    // c1 = s*Box(out), c2 = s*Box(out^2); y = out / (sqrt(c2-c1^2)+eps)
    vbox2_kernel<<<(NCOL2 * VNSEG) / 256, 256, 0, stream>>>(out, V1, V3);
    hbox_final_kernel<<<NB * HH, 256, 0, stream>>>(V1, V3, out);
}